// Round 1
// baseline (1226.070 us; speedup 1.0000x reference)
//
#include <hip/hip_runtime.h>
#include <math.h>

#define NNODES 50000
#define NEDGES 800000
#define ETOT   850000      // NEDGES + NNODES self-loops
#define SLOPE  0.2f

__device__ __forceinline__ float leaky(float v) { return v > 0.f ? v : SLOPE * v; }

// float atomic max via signed/unsigned int compare trick (init must be -inf)
__device__ __forceinline__ void atomicMaxF(float* addr, float val) {
    val += 0.f;  // normalize -0.0 -> +0.0 so the sign-branch trick is safe
    if (val >= 0.f) atomicMax((int*)addr, __float_as_int(val));
    else            atomicMin((unsigned int*)addr, (unsigned int)__float_as_int(val));
}

__device__ __forceinline__ int esrc(const int* ei, int e) { return e < NEDGES ? ei[e]          : e - NEDGES; }
__device__ __forceinline__ int edst(const int* ei, int e) { return e < NEDGES ? ei[NEDGES + e] : e - NEDGES; }

__global__ void fill_k(float* __restrict__ p, float v, int n) {
    int i = blockIdx.x * blockDim.x + threadIdx.x;
    if (i < n) p[i] = v;
}

// ---------------- GEMM1: H[M,256] = X[M,256] @ W[256,256] ----------------
__global__ __launch_bounds__(256) void gemm1_k(const float* __restrict__ X,
                                               const float* __restrict__ W,
                                               float* __restrict__ H, int M) {
    __shared__ float As[16][128];
    __shared__ float Bs[16][128];
    int tid = threadIdx.x;
    int row0 = blockIdx.x * 128;
    int col0 = blockIdx.y * 128;
    int tx = tid & 15, ty = tid >> 4;
    float acc[8][8] = {};
    for (int k0 = 0; k0 < 256; k0 += 16) {
        #pragma unroll
        for (int p = 0; p < 2; ++p) {               // A tile: 128 rows x 16 k
            int f = tid + p * 256;
            int m = f >> 2, kq = (f & 3) * 4;
            int row = row0 + m;
            float4 v = make_float4(0.f, 0.f, 0.f, 0.f);
            if (row < M) v = *(const float4*)&X[row * 256 + k0 + kq];
            As[kq + 0][m] = v.x; As[kq + 1][m] = v.y;
            As[kq + 2][m] = v.z; As[kq + 3][m] = v.w;
        }
        #pragma unroll
        for (int p = 0; p < 2; ++p) {               // B tile: 16 k x 128 cols
            int f = tid + p * 256;
            int k = f >> 5, nq = (f & 31) * 4;
            *(float4*)&Bs[k][nq] = *(const float4*)&W[(k0 + k) * 256 + col0 + nq];
        }
        __syncthreads();
        #pragma unroll
        for (int k = 0; k < 16; ++k) {
            float a[8], b[8];
            *(float4*)&a[0] = *(const float4*)&As[k][ty * 8];
            *(float4*)&a[4] = *(const float4*)&As[k][ty * 8 + 4];
            *(float4*)&b[0] = *(const float4*)&Bs[k][tx * 8];
            *(float4*)&b[4] = *(const float4*)&Bs[k][tx * 8 + 4];
            #pragma unroll
            for (int i = 0; i < 8; ++i)
                #pragma unroll
                for (int j = 0; j < 8; ++j) acc[i][j] += a[i] * b[j];
        }
        __syncthreads();
    }
    #pragma unroll
    for (int i = 0; i < 8; ++i) {
        int row = row0 + ty * 8 + i;
        if (row < M) {
            float4 v0 = make_float4(acc[i][0], acc[i][1], acc[i][2], acc[i][3]);
            float4 v1 = make_float4(acc[i][4], acc[i][5], acc[i][6], acc[i][7]);
            *(float4*)&H[row * 256 + col0 + tx * 8]     = v0;
            *(float4*)&H[row * 256 + col0 + tx * 8 + 4] = v1;
        }
    }
}

// ---------------- alpha1: per (node, head) dots with att vectors ----------------
__global__ void alpha1_k(const float* __restrict__ H,
                         const float* __restrict__ att_s, const float* __restrict__ att_d,
                         float* __restrict__ as1, float* __restrict__ ad1) {
    int i = blockIdx.x * blockDim.x + threadIdx.x;  // i = n*4 + h
    if (i >= NNODES * 4) return;
    int h = i & 3, n = i >> 2;
    const float* hp = H + n * 256 + h * 64;
    const float* s = att_s + h * 64;
    const float* d = att_d + h * 64;
    float vs = 0.f, vd = 0.f;
    #pragma unroll 8
    for (int c = 0; c < 64; ++c) { float x = hp[c]; vs += x * s[c]; vd += x * d[c]; }
    as1[i] = vs; ad1[i] = vd;
}

// ---------------- layer-1 edge passes ----------------
__global__ void e1_max_k(const int* __restrict__ ei, const float* __restrict__ as1,
                         const float* __restrict__ ad1, float* __restrict__ m1) {
    int t = blockIdx.x * blockDim.x + threadIdx.x;  // t = e*4 + h
    if (t >= ETOT * 4) return;
    int e = t >> 2, h = t & 3;
    int s = esrc(ei, e), d = edst(ei, e);
    float l = leaky(as1[s * 4 + h] + ad1[d * 4 + h]);
    atomicMaxF(&m1[d * 4 + h], l);
}

__global__ void e1_sum_k(const int* __restrict__ ei, const float* __restrict__ as1,
                         const float* __restrict__ ad1, const float* __restrict__ m1,
                         float* __restrict__ d1) {
    int t = blockIdx.x * blockDim.x + threadIdx.x;
    if (t >= ETOT * 4) return;
    int e = t >> 2, h = t & 3;
    int s = esrc(ei, e), d = edst(ei, e);
    float l = leaky(as1[s * 4 + h] + ad1[d * 4 + h]);
    atomicAdd(&d1[d * 4 + h], expf(l - m1[d * 4 + h]));
}

__global__ void e1_agg_k(const int* __restrict__ ei, const float* __restrict__ as1,
                         const float* __restrict__ ad1, const float* __restrict__ m1,
                         const float* __restrict__ d1, const float* __restrict__ H,
                         float* __restrict__ agg) {
    long gid = (long)blockIdx.x * blockDim.x + threadIdx.x;   // ETOT*64 threads
    int e = (int)(gid >> 6);
    if (e >= ETOT) return;
    int c = (int)(gid & 63);
    int s = esrc(ei, e), d = edst(ei, e);
    #pragma unroll
    for (int h = 0; h < 4; ++h) {
        float l = leaky(as1[s * 4 + h] + ad1[d * 4 + h]);
        float w = expf(l - m1[d * 4 + h]) / d1[d * 4 + h];
        atomicAdd(&agg[d * 256 + h * 64 + c], w * H[s * 256 + h * 64 + c]);
    }
}

// ---------------- GEMM2 (fused relu + alpha2): wave per node ----------------
__global__ __launch_bounds__(64) void gemm2_k(const float* __restrict__ agg,
                                              const float* __restrict__ b1,
                                              const float* __restrict__ W2,
                                              const float* __restrict__ a2sw,
                                              const float* __restrict__ a2dw,
                                              float* __restrict__ h2,
                                              float* __restrict__ a2s, float* __restrict__ a2d) {
    int n = blockIdx.x;
    int lane = threadIdx.x;
    float p[8] = {};
    #pragma unroll
    for (int j = 0; j < 4; ++j) {
        int k = lane + j * 64;
        float xv = agg[n * 256 + k] + b1[k];
        xv = xv > 0.f ? xv : 0.f;                   // relu
        const float* wr = W2 + k * 8;
        #pragma unroll
        for (int c = 0; c < 8; ++c) p[c] += xv * wr[c];
    }
    #pragma unroll
    for (int off = 32; off; off >>= 1)
        #pragma unroll
        for (int c = 0; c < 8; ++c) p[c] += __shfl_xor(p[c], off, 64);
    if (lane == 0) {
        float vs = 0.f, vd = 0.f;
        #pragma unroll
        for (int c = 0; c < 8; ++c) {
            h2[n * 8 + c] = p[c];
            vs += p[c] * a2sw[c];
            vd += p[c] * a2dw[c];
        }
        a2s[n] = vs; a2d[n] = vd;
    }
}

// ---------------- layer-2 edge passes (heads=1, ch=8) ----------------
__global__ void e2_max_k(const int* __restrict__ ei, const float* __restrict__ a2s,
                         const float* __restrict__ a2d, float* __restrict__ m2) {
    int e = blockIdx.x * blockDim.x + threadIdx.x;
    if (e >= ETOT) return;
    int s = esrc(ei, e), d = edst(ei, e);
    float l = leaky(a2s[s] + a2d[d]);
    atomicMaxF(&m2[d], l);
}

__global__ void e2_sum_k(const int* __restrict__ ei, const float* __restrict__ a2s,
                         const float* __restrict__ a2d, const float* __restrict__ m2,
                         float* __restrict__ d2) {
    int e = blockIdx.x * blockDim.x + threadIdx.x;
    if (e >= ETOT) return;
    int s = esrc(ei, e), d = edst(ei, e);
    float l = leaky(a2s[s] + a2d[d]);
    atomicAdd(&d2[d], expf(l - m2[d]));
}

__global__ void e2_agg_k(const int* __restrict__ ei, const float* __restrict__ a2s,
                         const float* __restrict__ a2d, const float* __restrict__ m2,
                         const float* __restrict__ d2, const float* __restrict__ h2,
                         float* __restrict__ out2) {
    long gid = (long)blockIdx.x * blockDim.x + threadIdx.x;   // ETOT*8 threads
    int e = (int)(gid >> 3);
    if (e >= ETOT) return;
    int c = (int)(gid & 7);
    int s = esrc(ei, e), d = edst(ei, e);
    float l = leaky(a2s[s] + a2d[d]);
    float w = expf(l - m2[d]) / d2[d];
    atomicAdd(&out2[d * 8 + c], w * h2[s * 8 + c]);
}

// ---------------- final: + b2, log_softmax ----------------
__global__ void lsm_k(const float* __restrict__ out2, const float* __restrict__ b2,
                      float* __restrict__ out) {
    int n = blockIdx.x * blockDim.x + threadIdx.x;
    if (n >= NNODES) return;
    float v[8];
    float mx = -INFINITY;
    #pragma unroll
    for (int c = 0; c < 8; ++c) { v[c] = out2[n * 8 + c] + b2[c]; mx = fmaxf(mx, v[c]); }
    float se = 0.f;
    #pragma unroll
    for (int c = 0; c < 8; ++c) se += expf(v[c] - mx);
    float lse = mx + logf(se);
    #pragma unroll
    for (int c = 0; c < 8; ++c) out[n * 8 + c] = v[c] - lse;
}

extern "C" void kernel_launch(void* const* d_in, const int* in_sizes, int n_in,
                              void* d_out, int out_size, void* d_ws, size_t ws_size,
                              hipStream_t stream) {
    const float* x    = (const float*)d_in[0];
    const int*   ei   = (const int*)  d_in[1];
    const float* W1   = (const float*)d_in[2];
    const float* a1sw = (const float*)d_in[3];
    const float* a1dw = (const float*)d_in[4];
    const float* b1   = (const float*)d_in[5];
    const float* W2   = (const float*)d_in[6];
    const float* a2sw = (const float*)d_in[7];
    const float* a2dw = (const float*)d_in[8];
    const float* b2   = (const float*)d_in[9];
    float* out = (float*)d_out;

    float* ws = (float*)d_ws;
    float* h1   = ws;                  // 12,800,000
    float* agg1 = h1   + 12800000;     // 12,800,000  (zero region starts here)
    float* d1   = agg1 + 12800000;     //    200,000
    float* d2   = d1   + 200000;       //     50,000
    float* out2 = d2   + 50000;        //    400,000  (zero region ends)
    float* m1   = out2 + 400000;       //    200,000  (-inf region starts)
    float* m2   = m1   + 200000;       //     50,000  (-inf region ends)
    float* as1  = m2   + 50000;        //    200,000
    float* ad1  = as1  + 200000;       //    200,000
    float* h2   = ad1  + 200000;       //    400,000
    float* a2s  = h2   + 400000;       //     50,000
    float* a2d  = a2s  + 50000;        //     50,000

    const int ZN = 12800000 + 200000 + 50000 + 400000;  // agg1..out2
    const int MN = 200000 + 50000;                      // m1..m2
    fill_k<<<(ZN + 255) / 256, 256, 0, stream>>>(agg1, 0.f, ZN);
    fill_k<<<(MN + 255) / 256, 256, 0, stream>>>(m1, -INFINITY, MN);

    dim3 g1((NNODES + 127) / 128, 2);
    gemm1_k<<<g1, 256, 0, stream>>>(x, W1, h1, NNODES);

    alpha1_k<<<(NNODES * 4 + 255) / 256, 256, 0, stream>>>(h1, a1sw, a1dw, as1, ad1);

    e1_max_k<<<(ETOT * 4 + 255) / 256, 256, 0, stream>>>(ei, as1, ad1, m1);
    e1_sum_k<<<(ETOT * 4 + 255) / 256, 256, 0, stream>>>(ei, as1, ad1, m1, d1);
    e1_agg_k<<<(int)(((long)ETOT * 64 + 255) / 256), 256, 0, stream>>>(ei, as1, ad1, m1, d1, h1, agg1);

    gemm2_k<<<NNODES, 64, 0, stream>>>(agg1, b1, W2, a2sw, a2dw, h2, a2s, a2d);

    e2_max_k<<<(ETOT + 255) / 256, 256, 0, stream>>>(ei, a2s, a2d, m2);
    e2_sum_k<<<(ETOT + 255) / 256, 256, 0, stream>>>(ei, a2s, a2d, m2, d2);
    e2_agg_k<<<(int)(((long)ETOT * 8 + 255) / 256), 256, 0, stream>>>(ei, a2s, a2d, m2, d2, h2, out2);

    lsm_k<<<(NNODES + 255) / 256, 256, 0, stream>>>(out2, b2, out);
}

// Round 2
// 606.736 us; speedup vs baseline: 2.0208x; 2.0208x over previous
//
#include <hip/hip_runtime.h>
#include <math.h>

#define NNODES 50000
#define NEDGES 800000
#define ETOT   850000      // NEDGES + NNODES self-loops
#define SLOPE  0.2f
#define NB     196         // ceil(NNODES/256) scan blocks

__device__ __forceinline__ float leaky(float v) { return v > 0.f ? v : SLOPE * v; }

__device__ __forceinline__ int esrc(const int* ei, int e) { return e < NEDGES ? ei[e]          : e - NEDGES; }
__device__ __forceinline__ int edst(const int* ei, int e) { return e < NEDGES ? ei[NEDGES + e] : e - NEDGES; }

__global__ void filli_k(int* __restrict__ p, int v, int n) {
    int i = blockIdx.x * blockDim.x + threadIdx.x;
    if (i < n) p[i] = v;
}

// ---------------- CSR build ----------------
__global__ void hist_k(const int* __restrict__ ei, int* __restrict__ cnt) {
    int e = blockIdx.x * blockDim.x + threadIdx.x;
    if (e >= ETOT) return;
    atomicAdd(&cnt[edst(ei, e)], 1);
}

__global__ void scan1_k(const int* __restrict__ cnt, int* __restrict__ incl,
                        int* __restrict__ bsum) {
    __shared__ int s[256];
    int i = blockIdx.x * 256 + threadIdx.x;
    int v = (i < NNODES) ? cnt[i] : 0;
    s[threadIdx.x] = v;
    __syncthreads();
    #pragma unroll
    for (int off = 1; off < 256; off <<= 1) {
        int t = (threadIdx.x >= off) ? s[threadIdx.x - off] : 0;
        __syncthreads();
        s[threadIdx.x] += t;
        __syncthreads();
    }
    if (i < NNODES) incl[i] = s[threadIdx.x];
    if (threadIdx.x == 255) bsum[blockIdx.x] = s[255];
}

__global__ void scan2_k(const int* __restrict__ bsum, int* __restrict__ boff) {
    __shared__ int s[256];
    int v = (threadIdx.x < NB) ? bsum[threadIdx.x] : 0;
    s[threadIdx.x] = v;
    __syncthreads();
    #pragma unroll
    for (int off = 1; off < 256; off <<= 1) {
        int t = (threadIdx.x >= off) ? s[threadIdx.x - off] : 0;
        __syncthreads();
        s[threadIdx.x] += t;
        __syncthreads();
    }
    boff[threadIdx.x] = s[threadIdx.x] - v;   // exclusive
}

__global__ void rs_k(const int* __restrict__ incl, const int* __restrict__ cnt,
                     const int* __restrict__ boff, int* __restrict__ rs,
                     int* __restrict__ cur) {
    int i = blockIdx.x * blockDim.x + threadIdx.x;
    if (i >= NNODES) return;
    int v = incl[i] - cnt[i] + boff[i >> 8];
    rs[i] = v; cur[i] = v;
}

__global__ void scatter_k(const int* __restrict__ ei, int* __restrict__ cur,
                          int* __restrict__ srcs) {
    int e = blockIdx.x * blockDim.x + threadIdx.x;
    if (e >= ETOT) return;
    int d = edst(ei, e), s = esrc(ei, e);
    int pos = atomicAdd(&cur[d], 1);
    srcs[pos] = s;
}

// ---------------- GEMM1: H[M,256] = X[M,256] @ W[256,256] ----------------
__global__ __launch_bounds__(256) void gemm1_k(const float* __restrict__ X,
                                               const float* __restrict__ W,
                                               float* __restrict__ H, int M) {
    __shared__ float As[16][128];
    __shared__ float Bs[16][128];
    int tid = threadIdx.x;
    int row0 = blockIdx.x * 128;
    int col0 = blockIdx.y * 128;
    int tx = tid & 15, ty = tid >> 4;
    float acc[8][8] = {};
    for (int k0 = 0; k0 < 256; k0 += 16) {
        #pragma unroll
        for (int p = 0; p < 2; ++p) {
            int f = tid + p * 256;
            int m = f >> 2, kq = (f & 3) * 4;
            int row = row0 + m;
            float4 v = make_float4(0.f, 0.f, 0.f, 0.f);
            if (row < M) v = *(const float4*)&X[row * 256 + k0 + kq];
            As[kq + 0][m] = v.x; As[kq + 1][m] = v.y;
            As[kq + 2][m] = v.z; As[kq + 3][m] = v.w;
        }
        #pragma unroll
        for (int p = 0; p < 2; ++p) {
            int f = tid + p * 256;
            int k = f >> 5, nq = (f & 31) * 4;
            *(float4*)&Bs[k][nq] = *(const float4*)&W[(k0 + k) * 256 + col0 + nq];
        }
        __syncthreads();
        #pragma unroll
        for (int k = 0; k < 16; ++k) {
            float a[8], b[8];
            *(float4*)&a[0] = *(const float4*)&As[k][ty * 8];
            *(float4*)&a[4] = *(const float4*)&As[k][ty * 8 + 4];
            *(float4*)&b[0] = *(const float4*)&Bs[k][tx * 8];
            *(float4*)&b[4] = *(const float4*)&Bs[k][tx * 8 + 4];
            #pragma unroll
            for (int i = 0; i < 8; ++i)
                #pragma unroll
                for (int j = 0; j < 8; ++j) acc[i][j] += a[i] * b[j];
        }
        __syncthreads();
    }
    #pragma unroll
    for (int i = 0; i < 8; ++i) {
        int row = row0 + ty * 8 + i;
        if (row < M) {
            float4 v0 = make_float4(acc[i][0], acc[i][1], acc[i][2], acc[i][3]);
            float4 v1 = make_float4(acc[i][4], acc[i][5], acc[i][6], acc[i][7]);
            *(float4*)&H[row * 256 + col0 + tx * 8]     = v0;
            *(float4*)&H[row * 256 + col0 + tx * 8 + 4] = v1;
        }
    }
}

// ---------------- alpha1: per (node, head) dots with att vectors ----------------
__global__ void alpha1_k(const float* __restrict__ H,
                         const float* __restrict__ att_s, const float* __restrict__ att_d,
                         float* __restrict__ as1, float* __restrict__ ad1) {
    int i = blockIdx.x * blockDim.x + threadIdx.x;  // i = n*4 + h
    if (i >= NNODES * 4) return;
    int h = i & 3, n = i >> 2;
    const float* hp = H + n * 256 + h * 64;
    const float* s = att_s + h * 64;
    const float* d = att_d + h * 64;
    float vs = 0.f, vd = 0.f;
    #pragma unroll 8
    for (int c = 0; c < 64; ++c) { float x = hp[c]; vs += x * s[c]; vd += x * d[c]; }
    as1[i] = vs; ad1[i] = vd;
}

// ---------------- fused layer-1: softmax-gather + relu + GEMM2 + alpha2 ----------------
__global__ __launch_bounds__(256) void f1_k(const int* __restrict__ rs,
                                            const int* __restrict__ cnt,
                                            const int* __restrict__ srcs,
                                            const float* __restrict__ as1,
                                            const float* __restrict__ ad1,
                                            const float* __restrict__ H,
                                            const float* __restrict__ b1,
                                            const float* __restrict__ W2,
                                            const float* __restrict__ a2sw,
                                            const float* __restrict__ a2dw,
                                            float* __restrict__ h2,
                                            float* __restrict__ a2s,
                                            float* __restrict__ a2d) {
    int d = blockIdx.x;
    int lane = threadIdx.x & 63, h = threadIdx.x >> 6;
    int start = rs[d], deg = cnt[d];
    float adv = ad1[d * 4 + h];

    // pass 1: per-head max over incoming edges
    float m = -INFINITY;
    for (int j = lane; j < deg; j += 64) {
        int s = srcs[start + j];
        m = fmaxf(m, leaky(as1[s * 4 + h] + adv));
    }
    #pragma unroll
    for (int off = 32; off; off >>= 1) m = fmaxf(m, __shfl_xor(m, off, 64));

    // pass 2: denom
    float den = 0.f;
    for (int j = lane; j < deg; j += 64) {
        int s = srcs[start + j];
        den += expf(leaky(as1[s * 4 + h] + adv) - m);
    }
    #pragma unroll
    for (int off = 32; off; off >>= 1) den += __shfl_xor(den, off, 64);
    float rden = 1.f / den;

    // pass 3: weighted gather, chunks of 64 edges buffered in LDS
    __shared__ float wbuf[4][64];
    __shared__ int   sbuf[64];
    float acc = 0.f;
    for (int base = 0; base < deg; base += 64) {
        int j = base + lane;
        int s = 0; float w = 0.f;
        if (j < deg) {
            s = srcs[start + j];
            w = expf(leaky(as1[s * 4 + h] + adv) - m) * rden;
        }
        wbuf[h][lane] = w;
        if (h == 0) sbuf[lane] = s;
        __syncthreads();
        int lim = min(64, deg - base);
        for (int t = 0; t < lim; ++t) {
            int s2 = sbuf[t];
            float w2 = wbuf[h][t];
            acc += w2 * H[(long)s2 * 256 + h * 64 + lane];
        }
        __syncthreads();
    }

    // relu(acc + b1) then fused GEMM2 (256 -> 8) + alpha2 dots
    int k = threadIdx.x;
    float xv = acc + b1[k];
    xv = xv > 0.f ? xv : 0.f;
    float p[8];
    const float* wr = W2 + k * 8;
    #pragma unroll
    for (int c = 0; c < 8; ++c) p[c] = xv * wr[c];
    #pragma unroll
    for (int off = 32; off; off >>= 1)
        #pragma unroll
        for (int c = 0; c < 8; ++c) p[c] += __shfl_xor(p[c], off, 64);
    __shared__ float pp[4][8];
    if (lane == 0)
        #pragma unroll
        for (int c = 0; c < 8; ++c) pp[h][c] = p[c];
    __syncthreads();
    if (threadIdx.x < 8) {
        int c = threadIdx.x;
        float v = pp[0][c] + pp[1][c] + pp[2][c] + pp[3][c];
        h2[d * 8 + c] = v;
        pp[0][c] = v;
    }
    __syncthreads();
    if (threadIdx.x == 0) {
        float vs = 0.f, vd = 0.f;
        #pragma unroll
        for (int c = 0; c < 8; ++c) { vs += pp[0][c] * a2sw[c]; vd += pp[0][c] * a2dw[c]; }
        a2s[d] = vs; a2d[d] = vd;
    }
}

// ---------------- fused layer-2: softmax-gather + bias + log_softmax ----------------
__global__ __launch_bounds__(64) void f2_k(const int* __restrict__ rs,
                                           const int* __restrict__ cnt,
                                           const int* __restrict__ srcs,
                                           const float* __restrict__ a2s,
                                           const float* __restrict__ a2d,
                                           const float* __restrict__ h2,
                                           const float* __restrict__ b2,
                                           float* __restrict__ out) {
    int d = blockIdx.x, lane = threadIdx.x;
    int start = rs[d], deg = cnt[d];
    float adv = a2d[d];

    float m = -INFINITY;
    for (int j = lane; j < deg; j += 64) {
        int s = srcs[start + j];
        m = fmaxf(m, leaky(a2s[s] + adv));
    }
    #pragma unroll
    for (int off = 32; off; off >>= 1) m = fmaxf(m, __shfl_xor(m, off, 64));

    float den = 0.f;
    for (int j = lane; j < deg; j += 64) {
        int s = srcs[start + j];
        den += expf(leaky(a2s[s] + adv) - m);
    }
    #pragma unroll
    for (int off = 32; off; off >>= 1) den += __shfl_xor(den, off, 64);
    float rden = 1.f / den;

    float acc[8] = {};
    for (int j = lane; j < deg; j += 64) {
        int s = srcs[start + j];
        float w = expf(leaky(a2s[s] + adv) - m) * rden;
        const float* hp = h2 + s * 8;
        #pragma unroll
        for (int c = 0; c < 8; ++c) acc[c] += w * hp[c];
    }
    #pragma unroll
    for (int off = 32; off; off >>= 1)
        #pragma unroll
        for (int c = 0; c < 8; ++c) acc[c] += __shfl_xor(acc[c], off, 64);

    if (lane == 0) {
        float v[8];
        float mx = -INFINITY;
        #pragma unroll
        for (int c = 0; c < 8; ++c) { v[c] = acc[c] + b2[c]; mx = fmaxf(mx, v[c]); }
        float se = 0.f;
        #pragma unroll
        for (int c = 0; c < 8; ++c) se += expf(v[c] - mx);
        float lse = mx + logf(se);
        #pragma unroll
        for (int c = 0; c < 8; ++c) out[d * 8 + c] = v[c] - lse;
    }
}

extern "C" void kernel_launch(void* const* d_in, const int* in_sizes, int n_in,
                              void* d_out, int out_size, void* d_ws, size_t ws_size,
                              hipStream_t stream) {
    const float* x    = (const float*)d_in[0];
    const int*   ei   = (const int*)  d_in[1];
    const float* W1   = (const float*)d_in[2];
    const float* a1sw = (const float*)d_in[3];
    const float* a1dw = (const float*)d_in[4];
    const float* b1   = (const float*)d_in[5];
    const float* W2   = (const float*)d_in[6];
    const float* a2sw = (const float*)d_in[7];
    const float* a2dw = (const float*)d_in[8];
    const float* b2   = (const float*)d_in[9];
    float* out = (float*)d_out;

    float* ws = (float*)d_ws;
    float* h1   = ws;                   // 12,800,000 f
    float* as1  = h1  + 12800000;       //    200,000 f
    float* ad1  = as1 + 200000;         //    200,000 f
    float* h2   = ad1 + 200000;         //    400,000 f
    float* a2s  = h2  + 400000;         //     50,000 f
    float* a2d  = a2s + 50000;          //     50,000 f
    int*   cnt  = (int*)(a2d + 50000);  //     50,000 i  (zero region start)
    int*   bsum = cnt  + 50000;         //        256 i  (zero region end)
    int*   incl = bsum + 256;           //     50,000 i
    int*   boff = incl + 50000;         //        256 i
    int*   rs   = boff + 256;           //     50,000 i
    int*   cur  = rs   + 50000;         //     50,000 i
    int*   srcs = cur  + 50000;         //    850,000 i

    // ---- CSR build (dst-sorted) ----
    filli_k<<<(50256 + 255) / 256, 256, 0, stream>>>(cnt, 0, 50256);
    hist_k<<<(ETOT + 255) / 256, 256, 0, stream>>>(ei, cnt);
    scan1_k<<<NB, 256, 0, stream>>>(cnt, incl, bsum);
    scan2_k<<<1, 256, 0, stream>>>(bsum, boff);
    rs_k<<<(NNODES + 255) / 256, 256, 0, stream>>>(incl, cnt, boff, rs, cur);
    scatter_k<<<(ETOT + 255) / 256, 256, 0, stream>>>(ei, cur, srcs);

    // ---- layer 1 projection + attention coefficients ----
    dim3 g1((NNODES + 127) / 128, 2);
    gemm1_k<<<g1, 256, 0, stream>>>(x, W1, h1, NNODES);
    alpha1_k<<<(NNODES * 4 + 255) / 256, 256, 0, stream>>>(h1, a1sw, a1dw, as1, ad1);

    // ---- fused layer-1 gather + GEMM2 + alpha2 ----
    f1_k<<<NNODES, 256, 0, stream>>>(rs, cnt, srcs, as1, ad1, h1, b1, W2,
                                     a2sw, a2dw, h2, a2s, a2d);

    // ---- fused layer-2 gather + log_softmax ----
    f2_k<<<NNODES, 64, 0, stream>>>(rs, cnt, srcs, a2s, a2d, h2, b2, out);
}

// Round 3
// 509.326 us; speedup vs baseline: 2.4072x; 1.1913x over previous
//
#include <hip/hip_runtime.h>
#include <math.h>

#define NNODES 50000
#define NEDGES 800000
#define ETOT   850000      // NEDGES + NNODES self-loops
#define SLOPE  0.2f
#define NB     196         // ceil(NNODES/256) scan blocks

typedef unsigned short ushort_t;
typedef unsigned int   uint_t;

__device__ __forceinline__ float leaky(float v) { return v > 0.f ? v : SLOPE * v; }

__device__ __forceinline__ ushort_t f2bf(float f) {       // fp32 -> bf16 RNE
    uint_t u = __float_as_uint(f);
    uint_t r = (u + 0x7fffu + ((u >> 16) & 1u)) >> 16;
    return (ushort_t)r;
}
__device__ __forceinline__ float bf2f(uint_t lo16) { return __uint_as_float(lo16 << 16); }

__device__ __forceinline__ int esrc(const int* ei, int e) { return e < NEDGES ? ei[e]          : e - NEDGES; }
__device__ __forceinline__ int edst(const int* ei, int e) { return e < NEDGES ? ei[NEDGES + e] : e - NEDGES; }

__global__ void filli_k(int* __restrict__ p, int v, int n) {
    int i = blockIdx.x * blockDim.x + threadIdx.x;
    if (i < n) p[i] = v;
}

// ---------------- CSR build ----------------
__global__ void hist_k(const int* __restrict__ ei, int* __restrict__ cnt) {
    int e = blockIdx.x * blockDim.x + threadIdx.x;
    if (e >= ETOT) return;
    atomicAdd(&cnt[edst(ei, e)], 1);
}

__global__ void scan1_k(const int* __restrict__ cnt, int* __restrict__ incl,
                        int* __restrict__ bsum) {
    __shared__ int s[256];
    int i = blockIdx.x * 256 + threadIdx.x;
    int v = (i < NNODES) ? cnt[i] : 0;
    s[threadIdx.x] = v;
    __syncthreads();
    #pragma unroll
    for (int off = 1; off < 256; off <<= 1) {
        int t = (threadIdx.x >= off) ? s[threadIdx.x - off] : 0;
        __syncthreads();
        s[threadIdx.x] += t;
        __syncthreads();
    }
    if (i < NNODES) incl[i] = s[threadIdx.x];
    if (threadIdx.x == 255) bsum[blockIdx.x] = s[255];
}

__global__ void scan2_k(const int* __restrict__ bsum, int* __restrict__ boff) {
    __shared__ int s[256];
    int v = (threadIdx.x < NB) ? bsum[threadIdx.x] : 0;
    s[threadIdx.x] = v;
    __syncthreads();
    #pragma unroll
    for (int off = 1; off < 256; off <<= 1) {
        int t = (threadIdx.x >= off) ? s[threadIdx.x - off] : 0;
        __syncthreads();
        s[threadIdx.x] += t;
        __syncthreads();
    }
    boff[threadIdx.x] = s[threadIdx.x] - v;   // exclusive
}

__global__ void rs_k(const int* __restrict__ incl, const int* __restrict__ cnt,
                     const int* __restrict__ boff, int* __restrict__ rs,
                     int* __restrict__ cur) {
    int i = blockIdx.x * blockDim.x + threadIdx.x;
    if (i >= NNODES) return;
    int v = incl[i] - cnt[i] + boff[i >> 8];
    rs[i] = v; cur[i] = v;
}

__global__ void scatter_k(const int* __restrict__ ei, int* __restrict__ cur,
                          int* __restrict__ srcs) {
    int e = blockIdx.x * blockDim.x + threadIdx.x;
    if (e >= ETOT) return;
    int d = edst(ei, e), s = esrc(ei, e);
    int pos = atomicAdd(&cur[d], 1);
    srcs[pos] = s;
}

// ------- GEMM1 + fused alpha1 + bf16 store: h1b = bf16(X@W1), as1/ad1 exact fp32 -------
__global__ __launch_bounds__(256) void gemm1_k(const float* __restrict__ X,
                                               const float* __restrict__ W,
                                               const float* __restrict__ att_s,
                                               const float* __restrict__ att_d,
                                               ushort_t* __restrict__ h1b,
                                               float* __restrict__ as1,
                                               float* __restrict__ ad1, int M) {
    __shared__ float As[16][128];
    __shared__ float Bs[16][128];
    int tid = threadIdx.x;
    int row0 = blockIdx.x * 128;
    int col0 = blockIdx.y * 128;
    int tx = tid & 15, ty = tid >> 4;
    float acc[8][8] = {};
    for (int k0 = 0; k0 < 256; k0 += 16) {
        #pragma unroll
        for (int p = 0; p < 2; ++p) {
            int f = tid + p * 256;
            int m = f >> 2, kq = (f & 3) * 4;
            int row = row0 + m;
            float4 v = make_float4(0.f, 0.f, 0.f, 0.f);
            if (row < M) v = *(const float4*)&X[row * 256 + k0 + kq];
            As[kq + 0][m] = v.x; As[kq + 1][m] = v.y;
            As[kq + 2][m] = v.z; As[kq + 3][m] = v.w;
        }
        #pragma unroll
        for (int p = 0; p < 2; ++p) {
            int f = tid + p * 256;
            int k = f >> 5, nq = (f & 31) * 4;
            *(float4*)&Bs[k][nq] = *(const float4*)&W[(k0 + k) * 256 + col0 + nq];
        }
        __syncthreads();
        #pragma unroll
        for (int k = 0; k < 16; ++k) {
            float a[8], b[8];
            *(float4*)&a[0] = *(const float4*)&As[k][ty * 8];
            *(float4*)&a[4] = *(const float4*)&As[k][ty * 8 + 4];
            *(float4*)&b[0] = *(const float4*)&Bs[k][tx * 8];
            *(float4*)&b[4] = *(const float4*)&Bs[k][tx * 8 + 4];
            #pragma unroll
            for (int i = 0; i < 8; ++i)
                #pragma unroll
                for (int j = 0; j < 8; ++j) acc[i][j] += a[i] * b[j];
        }
        __syncthreads();
    }
    // ---- epilogue: bf16 store + per-head alpha partials (exact fp32) ----
    int hh = (col0 >> 6) + (tx >> 3);             // head of this thread's 8 cols
    const float* asv = att_s + hh * 64 + (tx & 7) * 8;
    const float* adv = att_d + hh * 64 + (tx & 7) * 8;
    float ps[8], pd[8];
    #pragma unroll
    for (int i = 0; i < 8; ++i) {
        float vs = 0.f, vd = 0.f;
        #pragma unroll
        for (int j = 0; j < 8; ++j) { vs += acc[i][j] * asv[j]; vd += acc[i][j] * adv[j]; }
        ps[i] = vs; pd[i] = vd;
    }
    #pragma unroll
    for (int off = 1; off < 8; off <<= 1)
        #pragma unroll
        for (int i = 0; i < 8; ++i) {
            ps[i] += __shfl_xor(ps[i], off, 64);
            pd[i] += __shfl_xor(pd[i], off, 64);
        }
    #pragma unroll
    for (int i = 0; i < 8; ++i) {
        int row = row0 + ty * 8 + i;
        if (row < M) {
            uint_t w0 = (uint_t)f2bf(acc[i][0]) | ((uint_t)f2bf(acc[i][1]) << 16);
            uint_t w1 = (uint_t)f2bf(acc[i][2]) | ((uint_t)f2bf(acc[i][3]) << 16);
            uint_t w2 = (uint_t)f2bf(acc[i][4]) | ((uint_t)f2bf(acc[i][5]) << 16);
            uint_t w3 = (uint_t)f2bf(acc[i][6]) | ((uint_t)f2bf(acc[i][7]) << 16);
            uint4 pk = make_uint4(w0, w1, w2, w3);
            *(uint4*)&h1b[(size_t)row * 256 + col0 + tx * 8] = pk;
            if ((tx & 7) == 0) { as1[row * 4 + hh] = ps[i]; ad1[row * 4 + hh] = pd[i]; }
        }
    }
}

// ------- fused layer-1: softmax-gather (bf16 rows) + relu + GEMM2 + alpha2 -------
__global__ __launch_bounds__(256) void f1_k(const int* __restrict__ rs,
                                            const int* __restrict__ cnt,
                                            const int* __restrict__ srcs,
                                            const float* __restrict__ as1,
                                            const float* __restrict__ ad1,
                                            const ushort_t* __restrict__ h1b,
                                            const float* __restrict__ b1,
                                            const float* __restrict__ W2,
                                            const float* __restrict__ a2sw,
                                            const float* __restrict__ a2dw,
                                            float* __restrict__ h2,
                                            float* __restrict__ a2s,
                                            float* __restrict__ a2d) {
    int d = blockIdx.x;
    int tid = threadIdx.x;
    int h = tid >> 6, j = tid & 63;       // softmax phase: (head, edge-slot)
    int g = tid >> 5, lane2 = tid & 31;   // gather phase: (edge-group, row-pos)
    int hh2 = lane2 >> 3;                 // head of gather channels lane2*8..+7
    int start = rs[d], deg = cnt[d];
    float advv = ad1[d * 4 + h];

    __shared__ float wbuf[4][64];
    __shared__ int   sbuf[64];
    __shared__ float red[8][256];
    float acc8[8] = {};

    if (deg <= 64) {
        // one-shot: logit stays in a register across max/denom/weight
        int s = -1; float l = -INFINITY;
        if (j < deg) { s = srcs[start + j]; l = leaky(as1[s * 4 + h] + advv); }
        float m = l;
        #pragma unroll
        for (int off = 32; off; off >>= 1) m = fmaxf(m, __shfl_xor(m, off, 64));
        float ex = (j < deg) ? expf(l - m) : 0.f;
        float den = ex;
        #pragma unroll
        for (int off = 32; off; off >>= 1) den += __shfl_xor(den, off, 64);
        wbuf[h][j] = ex / den;
        if (h == 0) sbuf[j] = s;
        __syncthreads();
        for (int jj = g; jj < deg; jj += 8) {
            int s2 = sbuf[jj];
            float w2 = wbuf[hh2][jj];
            uint4 v = *(const uint4*)&h1b[(size_t)s2 * 256 + lane2 * 8];
            acc8[0] += w2 * bf2f(v.x & 0xffffu); acc8[1] += w2 * bf2f(v.x >> 16);
            acc8[2] += w2 * bf2f(v.y & 0xffffu); acc8[3] += w2 * bf2f(v.y >> 16);
            acc8[4] += w2 * bf2f(v.z & 0xffffu); acc8[5] += w2 * bf2f(v.z >> 16);
            acc8[6] += w2 * bf2f(v.w & 0xffffu); acc8[7] += w2 * bf2f(v.w >> 16);
        }
    } else {
        // generic chunked fallback
        float m = -INFINITY;
        for (int jc = j; jc < deg; jc += 64) {
            int s = srcs[start + jc];
            m = fmaxf(m, leaky(as1[s * 4 + h] + advv));
        }
        #pragma unroll
        for (int off = 32; off; off >>= 1) m = fmaxf(m, __shfl_xor(m, off, 64));
        float den = 0.f;
        for (int jc = j; jc < deg; jc += 64) {
            int s = srcs[start + jc];
            den += expf(leaky(as1[s * 4 + h] + advv) - m);
        }
        #pragma unroll
        for (int off = 32; off; off >>= 1) den += __shfl_xor(den, off, 64);
        float rden = 1.f / den;
        for (int base = 0; base < deg; base += 64) {
            int jc = base + j;
            int s = -1; float w = 0.f;
            if (jc < deg) {
                s = srcs[start + jc];
                w = expf(leaky(as1[s * 4 + h] + advv) - m) * rden;
            }
            wbuf[h][j] = w;
            if (h == 0) sbuf[j] = s;
            __syncthreads();
            int lim = min(64, deg - base);
            for (int jj = g; jj < lim; jj += 8) {
                int s2 = sbuf[jj];
                float w2 = wbuf[hh2][jj];
                uint4 v = *(const uint4*)&h1b[(size_t)s2 * 256 + lane2 * 8];
                acc8[0] += w2 * bf2f(v.x & 0xffffu); acc8[1] += w2 * bf2f(v.x >> 16);
                acc8[2] += w2 * bf2f(v.y & 0xffffu); acc8[3] += w2 * bf2f(v.y >> 16);
                acc8[4] += w2 * bf2f(v.z & 0xffffu); acc8[5] += w2 * bf2f(v.z >> 16);
                acc8[6] += w2 * bf2f(v.w & 0xffffu); acc8[7] += w2 * bf2f(v.w >> 16);
            }
            __syncthreads();
        }
    }

    // reduce the 8 edge-groups' partials
    *(float4*)&red[g][lane2 * 8]     = make_float4(acc8[0], acc8[1], acc8[2], acc8[3]);
    *(float4*)&red[g][lane2 * 8 + 4] = make_float4(acc8[4], acc8[5], acc8[6], acc8[7]);
    __syncthreads();
    int k = tid;
    float xv = red[0][k] + red[1][k] + red[2][k] + red[3][k]
             + red[4][k] + red[5][k] + red[6][k] + red[7][k] + b1[k];
    xv = xv > 0.f ? xv : 0.f;                     // relu

    // fused GEMM2 (256 -> 8) + alpha2 dots
    float p[8];
    const float* wr = W2 + k * 8;
    #pragma unroll
    for (int c = 0; c < 8; ++c) p[c] = xv * wr[c];
    #pragma unroll
    for (int off = 32; off; off >>= 1)
        #pragma unroll
        for (int c = 0; c < 8; ++c) p[c] += __shfl_xor(p[c], off, 64);
    __shared__ float pp[4][8];
    int lane = tid & 63, wave = tid >> 6;
    if (lane == 0)
        #pragma unroll
        for (int c = 0; c < 8; ++c) pp[wave][c] = p[c];
    __syncthreads();
    if (tid < 8) {
        int c = tid;
        float v = pp[0][c] + pp[1][c] + pp[2][c] + pp[3][c];
        h2[d * 8 + c] = v;
        pp[0][c] = v;
    }
    __syncthreads();
    if (tid == 0) {
        float vs = 0.f, vd = 0.f;
        #pragma unroll
        for (int c = 0; c < 8; ++c) { vs += pp[0][c] * a2sw[c]; vd += pp[0][c] * a2dw[c]; }
        a2s[d] = vs; a2d[d] = vd;
    }
}

// ---------------- fused layer-2: softmax-gather + bias + log_softmax ----------------
__global__ __launch_bounds__(64) void f2_k(const int* __restrict__ rs,
                                           const int* __restrict__ cnt,
                                           const int* __restrict__ srcs,
                                           const float* __restrict__ a2s,
                                           const float* __restrict__ a2d,
                                           const float* __restrict__ h2,
                                           const float* __restrict__ b2,
                                           float* __restrict__ out) {
    int d = blockIdx.x, lane = threadIdx.x;
    int start = rs[d], deg = cnt[d];
    float adv = a2d[d];

    float m = -INFINITY;
    for (int j = lane; j < deg; j += 64) {
        int s = srcs[start + j];
        m = fmaxf(m, leaky(a2s[s] + adv));
    }
    #pragma unroll
    for (int off = 32; off; off >>= 1) m = fmaxf(m, __shfl_xor(m, off, 64));

    float den = 0.f;
    for (int j = lane; j < deg; j += 64) {
        int s = srcs[start + j];
        den += expf(leaky(a2s[s] + adv) - m);
    }
    #pragma unroll
    for (int off = 32; off; off >>= 1) den += __shfl_xor(den, off, 64);
    float rden = 1.f / den;

    float acc[8] = {};
    for (int j = lane; j < deg; j += 64) {
        int s = srcs[start + j];
        float w = expf(leaky(a2s[s] + adv) - m) * rden;
        const float* hp = h2 + s * 8;
        #pragma unroll
        for (int c = 0; c < 8; ++c) acc[c] += w * hp[c];
    }
    #pragma unroll
    for (int off = 32; off; off >>= 1)
        #pragma unroll
        for (int c = 0; c < 8; ++c) acc[c] += __shfl_xor(acc[c], off, 64);

    if (lane == 0) {
        float v[8];
        float mx = -INFINITY;
        #pragma unroll
        for (int c = 0; c < 8; ++c) { v[c] = acc[c] + b2[c]; mx = fmaxf(mx, v[c]); }
        float se = 0.f;
        #pragma unroll
        for (int c = 0; c < 8; ++c) se += expf(v[c] - mx);
        float lse = mx + logf(se);
        #pragma unroll
        for (int c = 0; c < 8; ++c) out[d * 8 + c] = v[c] - lse;
    }
}

extern "C" void kernel_launch(void* const* d_in, const int* in_sizes, int n_in,
                              void* d_out, int out_size, void* d_ws, size_t ws_size,
                              hipStream_t stream) {
    const float* x    = (const float*)d_in[0];
    const int*   ei   = (const int*)  d_in[1];
    const float* W1   = (const float*)d_in[2];
    const float* a1sw = (const float*)d_in[3];
    const float* a1dw = (const float*)d_in[4];
    const float* b1   = (const float*)d_in[5];
    const float* W2   = (const float*)d_in[6];
    const float* a2sw = (const float*)d_in[7];
    const float* a2dw = (const float*)d_in[8];
    const float* b2   = (const float*)d_in[9];
    float* out = (float*)d_out;

    ushort_t* h1b = (ushort_t*)d_ws;       // 12,800,000 bf16 (25.6 MB)
    float* as1  = (float*)(h1b + 12800000);//    200,000 f
    float* ad1  = as1 + 200000;            //    200,000 f
    float* h2   = ad1 + 200000;            //    400,000 f
    float* a2s  = h2  + 400000;            //     50,000 f
    float* a2d  = a2s + 50000;             //     50,000 f
    int*   cnt  = (int*)(a2d + 50000);     //     50,000 i  (zero region start)
    int*   bsum = cnt  + 50000;            //        256 i  (zero region end)
    int*   incl = bsum + 256;              //     50,000 i
    int*   boff = incl + 50000;            //        256 i
    int*   rs   = boff + 256;              //     50,000 i
    int*   cur  = rs   + 50000;            //     50,000 i
    int*   srcs = cur  + 50000;            //    850,000 i

    // ---- CSR build (dst-sorted) ----
    filli_k<<<(50256 + 255) / 256, 256, 0, stream>>>(cnt, 0, 50256);
    hist_k<<<(ETOT + 255) / 256, 256, 0, stream>>>(ei, cnt);
    scan1_k<<<NB, 256, 0, stream>>>(cnt, incl, bsum);
    scan2_k<<<1, 256, 0, stream>>>(bsum, boff);
    rs_k<<<(NNODES + 255) / 256, 256, 0, stream>>>(incl, cnt, boff, rs, cur);
    scatter_k<<<(ETOT + 255) / 256, 256, 0, stream>>>(ei, cur, srcs);

    // ---- layer 1 projection (+ fused alpha1, bf16 store) ----
    dim3 g1((NNODES + 127) / 128, 2);
    gemm1_k<<<g1, 256, 0, stream>>>(x, W1, a1sw, a1dw, h1b, as1, ad1, NNODES);

    // ---- fused layer-1 gather + GEMM2 + alpha2 ----
    f1_k<<<NNODES, 256, 0, stream>>>(rs, cnt, srcs, as1, ad1, h1b, b1, W2,
                                     a2sw, a2dw, h2, a2s, a2d);

    // ---- fused layer-2 gather + log_softmax ----
    f2_k<<<NNODES, 64, 0, stream>>>(rs, cnt, srcs, a2s, a2d, h2, b2, out);
}

// Round 4
// 364.831 us; speedup vs baseline: 3.3607x; 1.3961x over previous
//
#include <hip/hip_runtime.h>
#include <math.h>

#define NNODES 50000
#define NEDGES 800000
#define ETOT   850000      // NEDGES + NNODES self-loops
#define SLOPE  0.2f
#define NB     196         // ceil(NNODES/256) scan blocks

typedef unsigned short ushort_t;
typedef unsigned int   uint_t;
typedef __attribute__((ext_vector_type(8))) __bf16 bf16x8;
typedef __attribute__((ext_vector_type(4))) float  floatx4;

__device__ __forceinline__ float leaky(float v) { return v > 0.f ? v : SLOPE * v; }

__device__ __forceinline__ ushort_t f2bf(float f) {       // fp32 -> bf16 RNE
    uint_t u = __float_as_uint(f);
    uint_t r = (u + 0x7fffu + ((u >> 16) & 1u)) >> 16;
    return (ushort_t)r;
}
__device__ __forceinline__ float bf2f(uint_t lo16) { return __uint_as_float(lo16 << 16); }

__device__ __forceinline__ float hsel(float4 v, int h) {  // v[h]
    float t0 = (h & 1) ? v.y : v.x;
    float t1 = (h & 1) ? v.w : v.z;
    return (h & 2) ? t1 : t0;
}

__device__ __forceinline__ int esrc(const int* ei, int e) { return e < NEDGES ? ei[e]          : e - NEDGES; }
__device__ __forceinline__ int edst(const int* ei, int e) { return e < NEDGES ? ei[NEDGES + e] : e - NEDGES; }

__global__ void filli_k(int* __restrict__ p, int v, int n) {
    int i = blockIdx.x * blockDim.x + threadIdx.x;
    if (i < n) p[i] = v;
}

// ---------------- W1 -> bf16, chunked layout W1c[kc][n][kk] (k = kc*32+kk) ----------------
__global__ void convw1_k(const float* __restrict__ W, ushort_t* __restrict__ W1c) {
    int i = blockIdx.x * 256 + threadIdx.x;   // 65536 elems, W row-major [k][n]
    int k = i >> 8, n = i & 255;
    W1c[(k >> 5) * 8192 + n * 32 + (k & 31)] = f2bf(W[i]);
}

// ---------------- CSR build ----------------
__global__ void hist_k(const int* __restrict__ ei, int* __restrict__ cnt) {
    int e = blockIdx.x * blockDim.x + threadIdx.x;
    if (e >= ETOT) return;
    atomicAdd(&cnt[edst(ei, e)], 1);
}

__global__ void scan1_k(const int* __restrict__ cnt, int* __restrict__ incl,
                        int* __restrict__ bsum) {
    __shared__ int s[256];
    int i = blockIdx.x * 256 + threadIdx.x;
    int v = (i < NNODES) ? cnt[i] : 0;
    s[threadIdx.x] = v;
    __syncthreads();
    #pragma unroll
    for (int off = 1; off < 256; off <<= 1) {
        int t = (threadIdx.x >= off) ? s[threadIdx.x - off] : 0;
        __syncthreads();
        s[threadIdx.x] += t;
        __syncthreads();
    }
    if (i < NNODES) incl[i] = s[threadIdx.x];
    if (threadIdx.x == 255) bsum[blockIdx.x] = s[255];
}

__global__ void scan2_k(const int* __restrict__ bsum, int* __restrict__ boff) {
    __shared__ int s[256];
    int v = (threadIdx.x < NB) ? bsum[threadIdx.x] : 0;
    s[threadIdx.x] = v;
    __syncthreads();
    #pragma unroll
    for (int off = 1; off < 256; off <<= 1) {
        int t = (threadIdx.x >= off) ? s[threadIdx.x - off] : 0;
        __syncthreads();
        s[threadIdx.x] += t;
        __syncthreads();
    }
    boff[threadIdx.x] = s[threadIdx.x] - v;   // exclusive
}

__global__ void rs_k(const int* __restrict__ incl, const int* __restrict__ cnt,
                     const int* __restrict__ boff, int* __restrict__ rs,
                     int* __restrict__ cur) {
    int i = blockIdx.x * blockDim.x + threadIdx.x;
    if (i >= NNODES) return;
    int v = incl[i] - cnt[i] + boff[i >> 8];
    rs[i] = v; cur[i] = v;
}

__global__ void scatter_k(const int* __restrict__ ei, int* __restrict__ cur,
                          int* __restrict__ srcs) {
    int e = blockIdx.x * blockDim.x + threadIdx.x;
    if (e >= ETOT) return;
    int d = edst(ei, e), s = esrc(ei, e);
    int pos = atomicAdd(&cur[d], 1);
    srcs[pos] = s;
}

// ------- MFMA GEMM1 (bf16) + fused alpha1: h1b = bf16(X@W1), as1/ad1 fp32 from acc -------
// block: 256 thr = 4 waves; BM=64, BN=256 (wave w owns cols/head w), BK=32, K=256.
__global__ __launch_bounds__(256) void gemm1_k(const float* __restrict__ X,
                                               const ushort_t* __restrict__ W1c,
                                               const float* __restrict__ att_s,
                                               const float* __restrict__ att_d,
                                               ushort_t* __restrict__ h1b,
                                               float* __restrict__ as1,
                                               float* __restrict__ ad1, int M) {
    __shared__ ushort_t Als[64 * 40];     // A tile [64][32] bf16, row pad to 40
    __shared__ ushort_t Bls[256 * 40];    // Bt tile [256 n][32 k] bf16, row pad to 40
    int tid = threadIdx.x;
    int row0 = blockIdx.x * 64;
    int wv = tid >> 6, lane = tid & 63, c15 = lane & 15, quad = lane >> 4;
    floatx4 acc[4][4] = {};               // [tm][tn]

    for (int kc = 0; kc < 8; ++kc) {
        __syncthreads();
        // stage A: 64 rows x 32 k, fp32 -> bf16
        {
            int r = tid >> 3, c4 = tid & 7;
            #pragma unroll
            for (int p = 0; p < 2; ++p) {
                int rr = r + p * 32;
                int row = row0 + rr;
                float4 v = make_float4(0.f, 0.f, 0.f, 0.f);
                if (row < M) v = *(const float4*)&X[(size_t)row * 256 + kc * 32 + c4 * 4];
                uint2 pk;
                pk.x = (uint_t)f2bf(v.x) | ((uint_t)f2bf(v.y) << 16);
                pk.y = (uint_t)f2bf(v.z) | ((uint_t)f2bf(v.w) << 16);
                *(uint2*)&Als[rr * 40 + c4 * 4] = pk;
            }
        }
        // stage Bt: read W1c chunk (contiguous) -> Bls[n][kk]
        {
            const uint4* srcp = (const uint4*)(W1c + kc * 8192);
            #pragma unroll
            for (int c = 0; c < 4; ++c) {
                int el = tid + c * 256;          // uint4 index, 1024 total
                uint4 v = srcp[el];
                int n = el >> 2, kk8 = (el & 3) * 8;
                *(uint4*)&Bls[n * 40 + kk8] = v;
            }
        }
        __syncthreads();
        uint4 af[4], bfr[4];
        #pragma unroll
        for (int t = 0; t < 4; ++t)
            af[t] = *(const uint4*)&Als[(t * 16 + c15) * 40 + quad * 8];
        #pragma unroll
        for (int t = 0; t < 4; ++t)
            bfr[t] = *(const uint4*)&Bls[(wv * 64 + t * 16 + c15) * 40 + quad * 8];
        #pragma unroll
        for (int tm = 0; tm < 4; ++tm)
            #pragma unroll
            for (int tn = 0; tn < 4; ++tn)
                acc[tm][tn] = __builtin_amdgcn_mfma_f32_16x16x32_bf16(
                    __builtin_bit_cast(bf16x8, af[tm]),
                    __builtin_bit_cast(bf16x8, bfr[tn]),
                    acc[tm][tn], 0, 0, 0);
    }

    // ---- epilogue: C/D layout col=lane&15, row=quad*4+reg ----
    float asv[4], adv[4];
    #pragma unroll
    for (int tn = 0; tn < 4; ++tn) {
        asv[tn] = att_s[wv * 64 + tn * 16 + c15];
        adv[tn] = att_d[wv * 64 + tn * 16 + c15];
    }
    float ps[4][4], pd[4][4];
    #pragma unroll
    for (int tm = 0; tm < 4; ++tm)
        #pragma unroll
        for (int r = 0; r < 4; ++r) {
            float vs = 0.f, vd = 0.f;
            #pragma unroll
            for (int tn = 0; tn < 4; ++tn) {
                float a = acc[tm][tn][r];
                vs += a * asv[tn]; vd += a * adv[tn];
            }
            ps[tm][r] = vs; pd[tm][r] = vd;
        }
    // bf16 stores of h1
    #pragma unroll
    for (int tm = 0; tm < 4; ++tm) {
        #pragma unroll
        for (int r = 0; r < 4; ++r) {
            int row = row0 + tm * 16 + quad * 4 + r;
            if (row < M) {
                #pragma unroll
                for (int tn = 0; tn < 4; ++tn)
                    h1b[(size_t)row * 256 + wv * 64 + tn * 16 + c15] = f2bf(acc[tm][tn][r]);
            }
        }
    }
    // reduce alpha partials across c15 (16 lanes)
    #pragma unroll
    for (int off = 1; off < 16; off <<= 1)
        #pragma unroll
        for (int tm = 0; tm < 4; ++tm)
            #pragma unroll
            for (int r = 0; r < 4; ++r) {
                ps[tm][r] += __shfl_xor(ps[tm][r], off, 64);
                pd[tm][r] += __shfl_xor(pd[tm][r], off, 64);
            }
    if (c15 == 0) {
        #pragma unroll
        for (int tm = 0; tm < 4; ++tm)
            #pragma unroll
            for (int r = 0; r < 4; ++r) {
                int row = row0 + tm * 16 + quad * 4 + r;
                if (row < M) {
                    as1[row * 4 + wv] = ps[tm][r];
                    ad1[row * 4 + wv] = pd[tm][r];
                }
            }
    }
}

// ------- fused layer-1: wave-per-node softmax-gather + relu + GEMM2 + alpha2 -------
// 4 nodes per 256-thr block; zero LDS, zero barriers.
__global__ __launch_bounds__(256) void f1_k(const int* __restrict__ rs,
                                            const int* __restrict__ cnt,
                                            const int* __restrict__ srcs,
                                            const float* __restrict__ as1,
                                            const float* __restrict__ ad1,
                                            const ushort_t* __restrict__ h1b,
                                            const float* __restrict__ b1,
                                            const float* __restrict__ W2,
                                            const float* __restrict__ a2sw,
                                            const float* __restrict__ a2dw,
                                            float* __restrict__ h2,
                                            float* __restrict__ a2s,
                                            float* __restrict__ a2d) {
    int node = blockIdx.x * 4 + (threadIdx.x >> 6);
    int lane = threadIdx.x & 63;
    int h = lane >> 4;                 // head of this lane's channels (lane*4..+3)
    int start = rs[node], deg = cnt[node];
    float4 advec = *(const float4*)&ad1[(size_t)node * 4];

    float m[4], dn[4];
    if (deg <= 64) {
        bool act = lane < deg;
        float4 av = make_float4(0.f, 0.f, 0.f, 0.f);
        if (act) {
            int s = srcs[start + lane];
            av = *(const float4*)&as1[(size_t)s * 4];
        }
        float l[4];
        l[0] = act ? leaky(av.x + advec.x) : -INFINITY;
        l[1] = act ? leaky(av.y + advec.y) : -INFINITY;
        l[2] = act ? leaky(av.z + advec.z) : -INFINITY;
        l[3] = act ? leaky(av.w + advec.w) : -INFINITY;
        #pragma unroll
        for (int i = 0; i < 4; ++i) m[i] = l[i];
        #pragma unroll
        for (int off = 32; off; off >>= 1)
            #pragma unroll
            for (int i = 0; i < 4; ++i) m[i] = fmaxf(m[i], __shfl_xor(m[i], off, 64));
        float ex[4];
        #pragma unroll
        for (int i = 0; i < 4; ++i) { ex[i] = act ? expf(l[i] - m[i]) : 0.f; dn[i] = ex[i]; }
        #pragma unroll
        for (int off = 32; off; off >>= 1)
            #pragma unroll
            for (int i = 0; i < 4; ++i) dn[i] += __shfl_xor(dn[i], off, 64);
    } else {
        #pragma unroll
        for (int i = 0; i < 4; ++i) m[i] = -INFINITY;
        for (int j = lane; j < deg; j += 64) {
            int s = srcs[start + j];
            float4 av = *(const float4*)&as1[(size_t)s * 4];
            m[0] = fmaxf(m[0], leaky(av.x + advec.x));
            m[1] = fmaxf(m[1], leaky(av.y + advec.y));
            m[2] = fmaxf(m[2], leaky(av.z + advec.z));
            m[3] = fmaxf(m[3], leaky(av.w + advec.w));
        }
        #pragma unroll
        for (int off = 32; off; off >>= 1)
            #pragma unroll
            for (int i = 0; i < 4; ++i) m[i] = fmaxf(m[i], __shfl_xor(m[i], off, 64));
        #pragma unroll
        for (int i = 0; i < 4; ++i) dn[i] = 0.f;
        for (int j = lane; j < deg; j += 64) {
            int s = srcs[start + j];
            float4 av = *(const float4*)&as1[(size_t)s * 4];
            dn[0] += expf(leaky(av.x + advec.x) - m[0]);
            dn[1] += expf(leaky(av.y + advec.y) - m[1]);
            dn[2] += expf(leaky(av.z + advec.z) - m[2]);
            dn[3] += expf(leaky(av.w + advec.w) - m[3]);
        }
        #pragma unroll
        for (int off = 32; off; off >>= 1)
            #pragma unroll
            for (int i = 0; i < 4; ++i) dn[i] += __shfl_xor(dn[i], off, 64);
    }

    // per-lane head-selected uniforms
    float advh = hsel(advec, h);
    float mh   = hsel(make_float4(m[0], m[1], m[2], m[3]), h);
    float rdh  = 1.f / hsel(make_float4(dn[0], dn[1], dn[2], dn[3]), h);

    // gather: 8 edges per batch, full 512B row per wave-instruction
    float acc[4] = {};
    int cmax = deg - 1;
    for (int base = 0; base < deg; base += 8) {
        #pragma unroll
        for (int u = 0; u < 8; ++u) {
            int e = base + u;
            int ce = min(e, cmax);
            int se = srcs[start + ce];                       // wave-broadcast, L1-hot
            float ash = as1[(size_t)se * 4 + h];            // L1-hot (phase 1 touched it)
            float ws = expf(leaky(ash + advh) - mh) * rdh;
            ws = (e < deg) ? ws : 0.f;
            uint2 v = *(const uint2*)&h1b[(size_t)se * 256 + lane * 4];
            acc[0] += ws * bf2f(v.x & 0xffffu);
            acc[1] += ws * bf2f(v.x >> 16);
            acc[2] += ws * bf2f(v.y & 0xffffu);
            acc[3] += ws * bf2f(v.y >> 16);
        }
    }

    // relu(acc + b1) -> GEMM2 (256 -> 8) -> alpha2 dots, all wave-local
    float4 bv = *(const float4*)&b1[lane * 4];
    float xv[4];
    xv[0] = fmaxf(acc[0] + bv.x, 0.f);
    xv[1] = fmaxf(acc[1] + bv.y, 0.f);
    xv[2] = fmaxf(acc[2] + bv.z, 0.f);
    xv[3] = fmaxf(acc[3] + bv.w, 0.f);
    float p[8] = {};
    #pragma unroll
    for (int q = 0; q < 4; ++q) {
        const float4* w2p = (const float4*)&W2[(size_t)(lane * 4 + q) * 8];
        float4 wa = w2p[0], wb = w2p[1];
        p[0] += xv[q] * wa.x; p[1] += xv[q] * wa.y; p[2] += xv[q] * wa.z; p[3] += xv[q] * wa.w;
        p[4] += xv[q] * wb.x; p[5] += xv[q] * wb.y; p[6] += xv[q] * wb.z; p[7] += xv[q] * wb.w;
    }
    #pragma unroll
    for (int off = 32; off; off >>= 1)
        #pragma unroll
        for (int c = 0; c < 8; ++c) p[c] += __shfl_xor(p[c], off, 64);
    if (lane == 0) {
        *(float4*)&h2[(size_t)node * 8]     = make_float4(p[0], p[1], p[2], p[3]);
        *(float4*)&h2[(size_t)node * 8 + 4] = make_float4(p[4], p[5], p[6], p[7]);
        float vs = 0.f, vd = 0.f;
        #pragma unroll
        for (int c = 0; c < 8; ++c) { vs += p[c] * a2sw[c]; vd += p[c] * a2dw[c]; }
        a2s[node] = vs; a2d[node] = vd;
    }
}

// ------- fused layer-2: wave-per-node softmax-gather + bias + log_softmax -------
__global__ __launch_bounds__(256) void f2_k(const int* __restrict__ rs,
                                            const int* __restrict__ cnt,
                                            const int* __restrict__ srcs,
                                            const float* __restrict__ a2s,
                                            const float* __restrict__ a2d,
                                            const float* __restrict__ h2,
                                            const float* __restrict__ b2,
                                            float* __restrict__ out) {
    int node = blockIdx.x * 4 + (threadIdx.x >> 6);
    int lane = threadIdx.x & 63;
    int start = rs[node], deg = cnt[node];
    float adv = a2d[node];

    float m, den;
    if (deg <= 64) {
        bool act = lane < deg;
        float l = -INFINITY;
        if (act) { int s = srcs[start + lane]; l = leaky(a2s[s] + adv); }
        m = l;
        #pragma unroll
        for (int off = 32; off; off >>= 1) m = fmaxf(m, __shfl_xor(m, off, 64));
        float ex = act ? expf(l - m) : 0.f;
        den = ex;
        #pragma unroll
        for (int off = 32; off; off >>= 1) den += __shfl_xor(den, off, 64);
    } else {
        m = -INFINITY;
        for (int j = lane; j < deg; j += 64) {
            int s = srcs[start + j];
            m = fmaxf(m, leaky(a2s[s] + adv));
        }
        #pragma unroll
        for (int off = 32; off; off >>= 1) m = fmaxf(m, __shfl_xor(m, off, 64));
        den = 0.f;
        for (int j = lane; j < deg; j += 64) {
            int s = srcs[start + j];
            den += expf(leaky(a2s[s] + adv) - m);
        }
        #pragma unroll
        for (int off = 32; off; off >>= 1) den += __shfl_xor(den, off, 64);
    }
    float rden = 1.f / den;

    int c = lane & 7, eg = lane >> 3;      // 8 edges per pass, 8 channels each
    float acc = 0.f;
    int cmax = deg - 1;
    for (int base = 0; base < deg; base += 16) {   // 2 batches per iter for ILP
        {
            int e = base + eg;
            int ce = min(e, cmax);
            int se = srcs[start + ce];
            float ws = (e < deg) ? expf(leaky(a2s[se] + adv) - m) * rden : 0.f;
            acc += ws * h2[(size_t)se * 8 + c];
        }
        {
            int e = base + 8 + eg;
            int ce = min(e, cmax);
            int se = srcs[start + ce];
            float ws = (e < deg) ? expf(leaky(a2s[se] + adv) - m) * rden : 0.f;
            acc += ws * h2[(size_t)se * 8 + c];
        }
    }
    #pragma unroll
    for (int off = 8; off < 64; off <<= 1) acc += __shfl_xor(acc, off, 64);

    float v = acc + b2[c];
    float mx = v;
    #pragma unroll
    for (int off = 1; off < 8; off <<= 1) mx = fmaxf(mx, __shfl_xor(mx, off, 64));
    float ex = expf(v - mx);
    float ss = ex;
    #pragma unroll
    for (int off = 1; off < 8; off <<= 1) ss += __shfl_xor(ss, off, 64);
    if (lane < 8) out[(size_t)node * 8 + c] = v - (mx + logf(ss));
}

extern "C" void kernel_launch(void* const* d_in, const int* in_sizes, int n_in,
                              void* d_out, int out_size, void* d_ws, size_t ws_size,
                              hipStream_t stream) {
    const float* x    = (const float*)d_in[0];
    const int*   ei   = (const int*)  d_in[1];
    const float* W1   = (const float*)d_in[2];
    const float* a1sw = (const float*)d_in[3];
    const float* a1dw = (const float*)d_in[4];
    const float* b1   = (const float*)d_in[5];
    const float* W2   = (const float*)d_in[6];
    const float* a2sw = (const float*)d_in[7];
    const float* a2dw = (const float*)d_in[8];
    const float* b2   = (const float*)d_in[9];
    float* out = (float*)d_out;

    ushort_t* h1b = (ushort_t*)d_ws;          // 12,800,000 bf16
    ushort_t* W1c = h1b + 12800000;           //     65,536 bf16 (chunked W1)
    float* as1  = (float*)(W1c + 65536);      //    200,000 f (16B-aligned)
    float* ad1  = as1 + 200000;               //    200,000 f
    float* h2   = ad1 + 200000;               //    400,000 f
    float* a2s  = h2  + 400000;               //     50,000 f
    float* a2d  = a2s + 50000;                //     50,000 f
    int*   cnt  = (int*)(a2d + 50000);        //     50,000 i (zero region start)
    int*   bsum = cnt  + 50000;               //        256 i (zero region end)
    int*   incl = bsum + 256;                 //     50,000 i
    int*   boff = incl + 50000;               //        256 i
    int*   rs   = boff + 256;                 //     50,000 i
    int*   cur  = rs   + 50000;               //     50,000 i
    int*   srcs = cur  + 50000;               //    850,000 i

    // ---- CSR build (dst-sorted) + W1 conversion ----
    filli_k<<<(50256 + 255) / 256, 256, 0, stream>>>(cnt, 0, 50256);
    convw1_k<<<256, 256, 0, stream>>>(W1, W1c);
    hist_k<<<(ETOT + 255) / 256, 256, 0, stream>>>(ei, cnt);
    scan1_k<<<NB, 256, 0, stream>>>(cnt, incl, bsum);
    scan2_k<<<1, 256, 0, stream>>>(bsum, boff);
    rs_k<<<(NNODES + 255) / 256, 256, 0, stream>>>(incl, cnt, boff, rs, cur);
    scatter_k<<<(ETOT + 255) / 256, 256, 0, stream>>>(ei, cur, srcs);

    // ---- layer 1 projection (MFMA bf16, fused alpha1) ----
    gemm1_k<<<(NNODES + 63) / 64, 256, 0, stream>>>(x, W1c, a1sw, a1dw, h1b, as1, ad1, NNODES);

    // ---- fused layer-1 gather + GEMM2 + alpha2 (wave per node) ----
    f1_k<<<NNODES / 4, 256, 0, stream>>>(rs, cnt, srcs, as1, ad1, h1b, b1, W2,
                                         a2sw, a2dw, h2, a2s, a2d);

    // ---- fused layer-2 gather + log_softmax (wave per node) ----
    f2_k<<<NNODES / 4, 256, 0, stream>>>(rs, cnt, srcs, a2s, a2d, h2, b2, out);
}